// Round 5
// baseline (5582.714 us; speedup 1.0000x reference)
//
#include <hip/hip_runtime.h>
#include <hip/hip_bf16.h>

// MultiSpeciesResistanceModel: R_ij = Ainv_ii + Ainv_jj - 2 Ainv_ij where
// A = L + 11^T/n (SPD).  pinv's J/n correction cancels in R exactly.
// Pipeline: MLP -> assemble A -> panel-256 Cholesky (fused single-WG diag
// factor kernel + parallel strip-trsm kernel + K=256 TRI syrk) -> W = G^{-1}
// by recursive block doubling -> Ainv = W^T W (split-K atomic, compact lower
// tiles) -> R.
//
// Workspace layout (floats), required ws_size >= 50,855,936 bytes:
//   Mc   : 2080 lower tiles * 4096           = 8,519,680
//   U    : union { cond(131072) -> GinvAll(262144) -> T(4,194,304) -> diag(4096) }
// A/G/W live in d_out[0 .. 16.7M) (the R region) until final_R overwrites it.

#define NN 4096
#define LDA 4096
#define NEDGE 131072
#define INVN (1.0f/4096.0f)

// ---------------- edge MLPs ----------------
__device__ __forceinline__ float mlp_eval(const float* __restrict__ w,
                                          const float* __restrict__ x) {
  float h1[32], h2[32];
#pragma unroll
  for (int o = 0; o < 32; o += 4) {
    float4 s = *(const float4*)&w[512 + o];
#pragma unroll
    for (int i = 0; i < 16; ++i) {
      float4 wv = *(const float4*)&w[i * 32 + o];
      s.x = fmaf(x[i], wv.x, s.x); s.y = fmaf(x[i], wv.y, s.y);
      s.z = fmaf(x[i], wv.z, s.z); s.w = fmaf(x[i], wv.w, s.w);
    }
    h1[o] = fmaxf(s.x, 0.f); h1[o+1] = fmaxf(s.y, 0.f);
    h1[o+2] = fmaxf(s.z, 0.f); h1[o+3] = fmaxf(s.w, 0.f);
  }
#pragma unroll
  for (int o = 0; o < 32; o += 4) {
    float4 s = *(const float4*)&w[1568 + o];
#pragma unroll
    for (int i = 0; i < 32; ++i) {
      float4 wv = *(const float4*)&w[544 + i * 32 + o];
      s.x = fmaf(h1[i], wv.x, s.x); s.y = fmaf(h1[i], wv.y, s.y);
      s.z = fmaf(h1[i], wv.z, s.z); s.w = fmaf(h1[i], wv.w, s.w);
    }
    h2[o] = fmaxf(s.x, 0.f); h2[o+1] = fmaxf(s.y, 0.f);
    h2[o+2] = fmaxf(s.z, 0.f); h2[o+3] = fmaxf(s.w, 0.f);
  }
  float out = w[1632];
#pragma unroll
  for (int i = 0; i < 32; ++i) out = fmaf(h2[i], w[1600 + i], out);
  return out;
}

__global__ __launch_bounds__(256) void mlp_kernel(
    const float* __restrict__ ef,
    const float* __restrict__ sW1, const float* __restrict__ sb1,
    const float* __restrict__ sW2, const float* __restrict__ sb2,
    const float* __restrict__ sW3, const float* __restrict__ sb3,
    const float* __restrict__ pW1, const float* __restrict__ pb1,
    const float* __restrict__ pW2, const float* __restrict__ pb2,
    const float* __restrict__ pW3, const float* __restrict__ pb3,
    float* __restrict__ outS, float* __restrict__ outP,
    float* __restrict__ cond) {
  __shared__ float w[3328];
  int t = threadIdx.x;
  for (int i = t; i < 512; i += 256) { w[i] = sW1[i]; w[1664 + i] = pW1[i]; }
  for (int i = t; i < 1024; i += 256) { w[544 + i] = sW2[i]; w[1664 + 544 + i] = pW2[i]; }
  if (t < 32) {
    w[512 + t] = sb1[t]; w[1568 + t] = sb2[t]; w[1600 + t] = sW3[t];
    w[1664 + 512 + t] = pb1[t]; w[1664 + 1568 + t] = pb2[t]; w[1664 + 1600 + t] = pW3[t];
  }
  if (t == 0) { w[1632] = sb3[0]; w[1664 + 1632] = pb3[0]; }
  __syncthreads();
  int e = blockIdx.x * 256 + t;
  float x[16];
#pragma unroll
  for (int i = 0; i < 16; i += 4) {
    float4 v = *(const float4*)&ef[(size_t)e * 16 + i];
    x[i] = v.x; x[i+1] = v.y; x[i+2] = v.z; x[i+3] = v.w;
  }
  float s = mlp_eval(w, x);
  float p = mlp_eval(w + 1664, x);
  outS[e] = s; outP[e] = p;
  float z = s + p;
  float sp = fmaxf(z, 0.f) + log1pf(expf(-fabsf(z)));
  cond[e] = 1.0f / (sp + 1e-4f);
}

// ---------------- A = J/n, then Laplacian scatter ----------------
__global__ __launch_bounds__(256) void init_A(float* __restrict__ A) {
  size_t q = (size_t)blockIdx.x * 256 + threadIdx.x;
  *(float4*)&A[q * 4] = make_float4(INVN, INVN, INVN, INVN);
}

__global__ __launch_bounds__(256) void zero_ws(float* __restrict__ P) {
  size_t q = (size_t)blockIdx.x * 256 + threadIdx.x;
  *(float4*)&P[q * 4] = make_float4(0.f, 0.f, 0.f, 0.f);
}

__global__ __launch_bounds__(256) void scatter_kernel(const int* __restrict__ ei,
                                                      const float* __restrict__ cond,
                                                      float* __restrict__ A) {
  int e = blockIdx.x * 256 + threadIdx.x;
  int i = ei[2 * e], j = ei[2 * e + 1];
  float c = cond[e];
  atomicAdd(&A[(size_t)i * (LDA + 1)], c);
  atomicAdd(&A[(size_t)j * (LDA + 1)], c);
  atomicAdd(&A[(size_t)i * LDA + j], -c);
  atomicAdd(&A[(size_t)j * LDA + i], -c);
}

// ---------------- wave-level 64x64 Cholesky + inverse (device fn) ----------------
__device__ __forceinline__ float rlane(float v, int l) {
  return __int_as_float(__builtin_amdgcn_readlane(__float_as_int(v), l));
}

// Lane i holds row i of the tile and row i of X = L^{-1} in registers.
// Writes L back to global and X (transposed: GT[c][r] = X[r][c]) to LDS.
__device__ __noinline__ void potf2_dev(float* __restrict__ A, int kt, int lane,
                                       float (* __restrict__ GT)[68]) {
  float* blk = A + (size_t)kt * 64 * (LDA + 1);
  float a[64], x[64];
#pragma unroll
  for (int c = 0; c < 64; c += 4) {
    float4 v = *(const float4*)&blk[(size_t)lane * LDA + c];
    a[c] = v.x; a[c+1] = v.y; a[c+2] = v.z; a[c+3] = v.w;
    x[c]   = (c   == lane) ? 1.f : 0.f;
    x[c+1] = (c+1 == lane) ? 1.f : 0.f;
    x[c+2] = (c+2 == lane) ? 1.f : 0.f;
    x[c+3] = (c+3 == lane) ? 1.f : 0.f;
  }
#pragma unroll
  for (int j = 0; j < 64; ++j) {
    float dj = rlane(a[j], j);
    float inv = 1.0f / sqrtf(dj);
    float lij = a[j] * inv;   // lane i>j: L[i][j]; lane j: sqrt(dj)
    a[j] = lij;
    float coefT = -lij;
    float sX = (lane == j) ? inv : 1.0f;
    float coefX = (lane > j) ? -lij : 0.0f;
#pragma unroll
    for (int c = j + 1; c < 64; ++c)
      a[c] = fmaf(coefT, rlane(lij, c), a[c]);
#pragma unroll
    for (int c = 0; c <= j; ++c) {
      float xjc = rlane(x[c], j) * inv;
      x[c] = fmaf(coefX, xjc, x[c] * sX);
    }
  }
#pragma unroll
  for (int c = 0; c < 64; c += 4)
    *(float4*)&blk[(size_t)lane * LDA + c] = make_float4(a[c], a[c+1], a[c+2], a[c+3]);
#pragma unroll
  for (int c = 0; c < 64; ++c) GT[c][lane] = x[c];
}

// 256-thread 64x64 syrk tile update: global C(ti_,tj_) -= LtA * LtB^T
// (operands in LDS, transposed layout Lt[k][r] = L[r][k])
__device__ __forceinline__ void syrk_tile(float* __restrict__ A, int t0, int ti_, int tj_,
                                          const float (* __restrict__ LtA)[68],
                                          const float (* __restrict__ LtB)[68], int gtid) {
  int tx = gtid & 15, ty = gtid >> 4;
  float acc[4][4] = {};
  for (int k = 0; k < 64; ++k) {
    float4 a4 = *(const float4*)&LtA[k][ty * 4];
    float4 b4 = *(const float4*)&LtB[k][tx * 4];
    float aa[4] = {a4.x, a4.y, a4.z, a4.w};
    float bb[4] = {b4.x, b4.y, b4.z, b4.w};
#pragma unroll
    for (int i = 0; i < 4; ++i)
#pragma unroll
      for (int jj = 0; jj < 4; ++jj) acc[i][jj] = fmaf(aa[i], bb[jj], acc[i][jj]);
  }
  float* C = A + ((size_t)(t0 + ti_) * 64) * LDA + (size_t)(t0 + tj_) * 64;
#pragma unroll
  for (int i = 0; i < 4; ++i) {
    float* p = &C[(size_t)(ty * 4 + i) * LDA + tx * 4];
    float4 c = *(float4*)p;
    c.x -= acc[i][0]; c.y -= acc[i][1]; c.z -= acc[i][2]; c.w -= acc[i][3];
    *(float4*)p = c;
  }
}

// ---------------- fused 256x256 diagonal-panel factorization ----------------
// One workgroup (512 thr). For kk=0..3: wave0 does register potf2+inverse of
// tile (kk,kk) CONCURRENT with grp1 applying the previous column's trailing
// updates (part2); then trsm tiles (i,kk); then eager update of (kk+1,kk+1)
// (part1) so the next potf2 can start immediately.
__global__ __launch_bounds__(512) void potrf_diag256(float* __restrict__ A,
                                                     float* __restrict__ GinvAll,
                                                     int p) {
  __shared__ float GT[64][68];     // X^T of current diag tile
  __shared__ float At[2][64][68];  // trsm staging per 256-thr group
  __shared__ float Lt[3][64][68];  // trsm results, transposed
  int tid = threadIdx.x;
  int wid = tid >> 6, lane = tid & 63;
  int grp = tid >> 8, gtid = tid & 255;
  int t0 = p * 4;
  for (int kk = 0; kk < 4; ++kk) {
    // region 1: potf2(kk) || part2 syrk (updates from column kk-1)
    if (wid == 0) {
      potf2_dev(A, t0 + kk, lane, GT);
    } else if (grp == 1) {
      const int TI_[5] = {2, 3, 2, 3, 3};
      const int TJ_[5] = {1, 1, 2, 2, 3};
#pragma unroll 5
      for (int t = 0; t < 5; ++t) {
        bool on = (kk == 1) || (kk == 2 && t >= 3);
        if (on)
          syrk_tile(A, t0, TI_[t], TJ_[t], Lt[TI_[t] - kk], Lt[TJ_[t] - kk], gtid);
      }
    }
    __syncthreads();
    // export Ginv64 of tile kk to global (GT stable until next phase)
    {
      int base = (t0 + kk) * 4096;
#pragma unroll 8
      for (int u = 0; u < 8; ++u) {
        int q = tid * 8 + u;
        GinvAll[base + q] = GT[q & 63][q >> 6];
      }
    }
    // step B: trsm tiles (i,kk), i=kk+1..3, 2 groups x 2 rounds
    for (int rnd = 0; rnd < 2; ++rnd) {
      int it = kk + 1 + rnd * 2 + grp;
      bool act = (it <= 3);
      if (act) {  // stage A tile (t0+it, t0+kk) transposed into At[grp]
        for (int q = gtid; q < 1024; q += 256) {
          int r = q >> 4, k4 = (q & 15) << 2;
          float4 v = *(const float4*)&A[((size_t)(t0 + it) * 64 + r) * LDA +
                                        (size_t)(t0 + kk) * 64 + k4];
          At[grp][k4 + 0][r] = v.x; At[grp][k4 + 1][r] = v.y;
          At[grp][k4 + 2][r] = v.z; At[grp][k4 + 3][r] = v.w;
        }
      }
      __syncthreads();
      if (act) {
        int tx = gtid & 15, ty = gtid >> 4;
        float acc[4][4] = {};
        for (int k = 0; k < 64; ++k) {
          float4 a4 = *(const float4*)&At[grp][k][ty * 4];
          float4 b4 = *(const float4*)&GT[k][tx * 4];
          float aa[4] = {a4.x, a4.y, a4.z, a4.w};
          float bb[4] = {b4.x, b4.y, b4.z, b4.w};
#pragma unroll
          for (int i = 0; i < 4; ++i)
#pragma unroll
            for (int jj = 0; jj < 4; ++jj) acc[i][jj] = fmaf(aa[i], bb[jj], acc[i][jj]);
        }
        int s = it - kk - 1;
#pragma unroll
        for (int jj = 0; jj < 4; ++jj)
          *(float4*)&Lt[s][tx * 4 + jj][ty * 4] =
              make_float4(acc[0][jj], acc[1][jj], acc[2][jj], acc[3][jj]);
        float* C = A + ((size_t)(t0 + it) * 64) * LDA + (size_t)(t0 + kk) * 64;
#pragma unroll
        for (int i = 0; i < 4; ++i)
          *(float4*)&C[(size_t)(ty * 4 + i) * LDA + tx * 4] =
              make_float4(acc[i][0], acc[i][1], acc[i][2], acc[i][3]);
      }
      __syncthreads();
    }
    // part1: eager update of (kk+1,kk+1) so next potf2 can run
    if (kk < 3 && grp == 0)
      syrk_tile(A, t0, kk + 1, kk + 1, Lt[0], Lt[0], gtid);
    __syncthreads();
  }
}

// ---------------- parallel panel trsm: L21 = A21 * Ldiag256^{-T} ----------------
// Each block owns a 64-row x 256-col strip in LDS; column-block sweep.
__global__ __launch_bounds__(256) void trsm_panel256(float* __restrict__ A,
                                                     const float* __restrict__ GinvAll,
                                                     int p) {
  __shared__ float Sr[64][260];
  __shared__ float Bt[64][68];
  int tid = threadIdx.x;
  int c0 = p * 256;
  int r0 = c0 + 256 + blockIdx.x * 64;
  for (int q = tid; q < 4096; q += 256) {
    int r = q >> 6, c4 = (q & 63) << 2;
    *(float4*)&Sr[r][c4] = *(const float4*)&A[(size_t)(r0 + r) * LDA + c0 + c4];
  }
  __syncthreads();
  int tx = tid & 15, ty = tid >> 4;
  for (int j = 0; j < 4; ++j) {
    float acc2[4][4] = {};
    for (int p2 = 0; p2 < j; ++p2) {
      // stage Ldiag[j][p2] transposed: Bt[k][c] = Ld[c][k]
      for (int q = tid; q < 1024; q += 256) {
        int c = q >> 4, k4 = (q & 15) << 2;
        float4 v = *(const float4*)&A[(size_t)(c0 + j * 64 + c) * LDA +
                                      c0 + p2 * 64 + k4];
        Bt[k4 + 0][c] = v.x; Bt[k4 + 1][c] = v.y;
        Bt[k4 + 2][c] = v.z; Bt[k4 + 3][c] = v.w;
      }
      __syncthreads();
      for (int k = 0; k < 64; ++k) {
        float a0 = Sr[ty * 4 + 0][p2 * 64 + k];
        float a1 = Sr[ty * 4 + 1][p2 * 64 + k];
        float a2 = Sr[ty * 4 + 2][p2 * 64 + k];
        float a3 = Sr[ty * 4 + 3][p2 * 64 + k];
        float4 b = *(const float4*)&Bt[k][tx * 4];
        acc2[0][0] = fmaf(a0, b.x, acc2[0][0]); acc2[0][1] = fmaf(a0, b.y, acc2[0][1]);
        acc2[0][2] = fmaf(a0, b.z, acc2[0][2]); acc2[0][3] = fmaf(a0, b.w, acc2[0][3]);
        acc2[1][0] = fmaf(a1, b.x, acc2[1][0]); acc2[1][1] = fmaf(a1, b.y, acc2[1][1]);
        acc2[1][2] = fmaf(a1, b.z, acc2[1][2]); acc2[1][3] = fmaf(a1, b.w, acc2[1][3]);
        acc2[2][0] = fmaf(a2, b.x, acc2[2][0]); acc2[2][1] = fmaf(a2, b.y, acc2[2][1]);
        acc2[2][2] = fmaf(a2, b.z, acc2[2][2]); acc2[2][3] = fmaf(a2, b.w, acc2[2][3]);
        acc2[3][0] = fmaf(a3, b.x, acc2[3][0]); acc2[3][1] = fmaf(a3, b.y, acc2[3][1]);
        acc2[3][2] = fmaf(a3, b.z, acc2[3][2]); acc2[3][3] = fmaf(a3, b.w, acc2[3][3]);
      }
      __syncthreads();
    }
    if (j > 0) {
#pragma unroll
      for (int i = 0; i < 4; ++i) {
        Sr[ty * 4 + i][j * 64 + tx * 4 + 0] -= acc2[i][0];
        Sr[ty * 4 + i][j * 64 + tx * 4 + 1] -= acc2[i][1];
        Sr[ty * 4 + i][j * 64 + tx * 4 + 2] -= acc2[i][2];
        Sr[ty * 4 + i][j * 64 + tx * 4 + 3] -= acc2[i][3];
      }
    }
    __syncthreads();
    // stage Ginv_j transposed
    {
      const float* G = GinvAll + (size_t)(p * 4 + j) * 4096;
      for (int q = tid; q < 1024; q += 256) {
        int c = q >> 4, k4 = (q & 15) << 2;
        float4 v = *(const float4*)&G[c * 64 + k4];
        Bt[k4 + 0][c] = v.x; Bt[k4 + 1][c] = v.y;
        Bt[k4 + 2][c] = v.z; Bt[k4 + 3][c] = v.w;
      }
    }
    __syncthreads();
    float acc3[4][4] = {};
    for (int k = 0; k < 64; ++k) {
      float a0 = Sr[ty * 4 + 0][j * 64 + k];
      float a1 = Sr[ty * 4 + 1][j * 64 + k];
      float a2 = Sr[ty * 4 + 2][j * 64 + k];
      float a3 = Sr[ty * 4 + 3][j * 64 + k];
      float4 b = *(const float4*)&Bt[k][tx * 4];
      acc3[0][0] = fmaf(a0, b.x, acc3[0][0]); acc3[0][1] = fmaf(a0, b.y, acc3[0][1]);
      acc3[0][2] = fmaf(a0, b.z, acc3[0][2]); acc3[0][3] = fmaf(a0, b.w, acc3[0][3]);
      acc3[1][0] = fmaf(a1, b.x, acc3[1][0]); acc3[1][1] = fmaf(a1, b.y, acc3[1][1]);
      acc3[1][2] = fmaf(a1, b.z, acc3[1][2]); acc3[1][3] = fmaf(a1, b.w, acc3[1][3]);
      acc3[2][0] = fmaf(a2, b.x, acc3[2][0]); acc3[2][1] = fmaf(a2, b.y, acc3[2][1]);
      acc3[2][2] = fmaf(a2, b.z, acc3[2][2]); acc3[2][3] = fmaf(a2, b.w, acc3[2][3]);
      acc3[3][0] = fmaf(a3, b.x, acc3[3][0]); acc3[3][1] = fmaf(a3, b.y, acc3[3][1]);
      acc3[3][2] = fmaf(a3, b.z, acc3[3][2]); acc3[3][3] = fmaf(a3, b.w, acc3[3][3]);
    }
    __syncthreads();
#pragma unroll
    for (int i = 0; i < 4; ++i) {
      Sr[ty * 4 + i][j * 64 + tx * 4 + 0] = acc3[i][0];
      Sr[ty * 4 + i][j * 64 + tx * 4 + 1] = acc3[i][1];
      Sr[ty * 4 + i][j * 64 + tx * 4 + 2] = acc3[i][2];
      Sr[ty * 4 + i][j * 64 + tx * 4 + 3] = acc3[i][3];
    }
    __syncthreads();
  }
  for (int q = tid; q < 4096; q += 256) {
    int r = q >> 6, c4 = (q & 63) << 2;
    *(float4*)&A[(size_t)(r0 + r) * LDA + c0 + c4] = *(float4*)&Sr[r][c4];
  }
}

// ---------------- generic 64x64-tile fp32 GEMM (doubling S=64) ----------------
template <bool TA, bool TB, bool ACCUM, bool LOWER, bool KST, bool CCOMP>
__global__ __launch_bounds__(256) void gemm64(
    const float* __restrict__ Ab, long long aZ, int lda,
    const float* __restrict__ Bb, long long bZ, int ldb,
    float* __restrict__ Cb, long long cZ, int ldc, int K, float alpha) {
  int ti = blockIdx.x, tj = blockIdx.y;
  if (LOWER && tj > ti) return;
  const float* A = Ab + (long long)blockIdx.z * aZ;
  const float* B = Bb + (long long)blockIdx.z * bZ;
  __shared__ float As[16][68], Bs[16][68];
  int tid = threadIdx.x;
  int tx = tid & 15, ty = tid >> 4;
  float acc[4][4] = {};
  int m0 = ti * 64, n0 = tj * 64;
  int k0 = KST ? ti * 64 : 0;
  for (int k = k0; k < K; k += 16) {
    if (!TA) {
      int r = tid >> 2, c4 = (tid & 3) * 4;
      float4 v = *(const float4*)&A[(size_t)(m0 + r) * lda + k + c4];
      As[c4 + 0][r] = v.x; As[c4 + 1][r] = v.y; As[c4 + 2][r] = v.z; As[c4 + 3][r] = v.w;
    } else {
      int r = tid >> 4, c4 = (tid & 15) * 4;
      *(float4*)&As[r][c4] = *(const float4*)&A[(size_t)(k + r) * lda + m0 + c4];
    }
    if (TB) {
      int r = tid >> 2, c4 = (tid & 3) * 4;
      float4 v = *(const float4*)&B[(size_t)(n0 + r) * ldb + k + c4];
      Bs[c4 + 0][r] = v.x; Bs[c4 + 1][r] = v.y; Bs[c4 + 2][r] = v.z; Bs[c4 + 3][r] = v.w;
    } else {
      int r = tid >> 4, c4 = (tid & 15) * 4;
      *(float4*)&Bs[r][c4] = *(const float4*)&B[(size_t)(k + r) * ldb + n0 + c4];
    }
    __syncthreads();
#pragma unroll
    for (int kk = 0; kk < 16; ++kk) {
      float4 av = *(const float4*)&As[kk][ty * 4];
      float4 bv = *(const float4*)&Bs[kk][tx * 4];
      float a[4] = {av.x, av.y, av.z, av.w};
      float b[4] = {bv.x, bv.y, bv.z, bv.w};
#pragma unroll
      for (int i = 0; i < 4; ++i)
#pragma unroll
        for (int jj = 0; jj < 4; ++jj) acc[i][jj] = fmaf(a[i], b[jj], acc[i][jj]);
    }
    __syncthreads();
  }
  float* C = Cb + (long long)blockIdx.z * cZ;
#pragma unroll
  for (int i = 0; i < 4; ++i) {
    size_t off = (size_t)(m0 + ty * 4 + i) * ldc + n0 + tx * 4;
    float4 c;
    if (ACCUM) {
      c = *(float4*)&C[off];
      c.x += alpha * acc[i][0]; c.y += alpha * acc[i][1];
      c.z += alpha * acc[i][2]; c.w += alpha * acc[i][3];
    } else {
      c.x = alpha * acc[i][0]; c.y = alpha * acc[i][1];
      c.z = alpha * acc[i][2]; c.w = alpha * acc[i][3];
    }
    *(float4*)&C[off] = c;
  }
}

// ---------------- 128x128-tile fp32 GEMM, 8x8 micro, conflict-free ----------------
// TRI: linear triangular grid.  KST: k starts at ti*128.  CCOMP: compact
// 64x64 lower tiles.  ATOMIC: atomicAdd outputs (CCOMP path).  KSPLIT:
// blockIdx.z in {0,1} splits K at 2048 (deterministic 2-addend atomics).
template <bool TA, bool TB, bool ACCUM, bool TRI, bool KST, bool CCOMP,
          bool ATOMIC, bool KSPLIT>
__global__ __launch_bounds__(256) void gemm128(
    const float* __restrict__ Ab, long long aZ, int lda,
    const float* __restrict__ Bb, long long bZ, int ldb,
    float* __restrict__ Cb, long long cZ, int ldc, int K, float alpha) {
  int ti, tj;
  if (TRI) {
    int bid = blockIdx.x;
    ti = (int)((sqrtf(8.0f * bid + 1.0f) - 1.0f) * 0.5f);
    while ((ti + 1) * (ti + 2) / 2 <= bid) ++ti;
    while (ti * (ti + 1) / 2 > bid) --ti;
    tj = bid - ti * (ti + 1) / 2;
  } else {
    ti = blockIdx.x; tj = blockIdx.y;
  }
  int k0 = KST ? ti * 128 : 0;
  int kEnd = K;
  if (KSPLIT) {
    if (blockIdx.z == 0) { kEnd = 2048; if (k0 >= kEnd) return; }
    else { k0 = (k0 > 2048) ? k0 : 2048; }
  }
  const float* A = KSPLIT ? Ab : Ab + (long long)blockIdx.z * aZ;
  const float* B = KSPLIT ? Bb : Bb + (long long)blockIdx.z * bZ;
  __shared__ float As[16][132], Bs[16][132];
  int tid = threadIdx.x;
  int tx = tid & 15, ty = tid >> 4;
  float acc[8][8] = {};
  int m0 = ti * 128, n0 = tj * 128;
  for (int k = k0; k < kEnd; k += 16) {
    if (!TA) {
      int r = tid >> 1, c8 = (tid & 1) * 8;
      const float* src = &A[(size_t)(m0 + r) * lda + k + c8];
      float4 v0 = *(const float4*)src;
      float4 v1 = *(const float4*)(src + 4);
      As[c8 + 0][r] = v0.x; As[c8 + 1][r] = v0.y; As[c8 + 2][r] = v0.z; As[c8 + 3][r] = v0.w;
      As[c8 + 4][r] = v1.x; As[c8 + 5][r] = v1.y; As[c8 + 6][r] = v1.z; As[c8 + 7][r] = v1.w;
    } else {
      int r = tid >> 4, c8 = (tid & 15) * 8;
      const float* src = &A[(size_t)(k + r) * lda + m0 + c8];
      *(float4*)&As[r][c8]     = *(const float4*)src;
      *(float4*)&As[r][c8 + 4] = *(const float4*)(src + 4);
    }
    if (TB) {
      int r = tid >> 1, c8 = (tid & 1) * 8;
      const float* src = &B[(size_t)(n0 + r) * ldb + k + c8];
      float4 v0 = *(const float4*)src;
      float4 v1 = *(const float4*)(src + 4);
      Bs[c8 + 0][r] = v0.x; Bs[c8 + 1][r] = v0.y; Bs[c8 + 2][r] = v0.z; Bs[c8 + 3][r] = v0.w;
      Bs[c8 + 4][r] = v1.x; Bs[c8 + 5][r] = v1.y; Bs[c8 + 6][r] = v1.z; Bs[c8 + 7][r] = v1.w;
    } else {
      int r = tid >> 4, c8 = (tid & 15) * 8;
      const float* src = &B[(size_t)(k + r) * ldb + n0 + c8];
      *(float4*)&Bs[r][c8]     = *(const float4*)src;
      *(float4*)&Bs[r][c8 + 4] = *(const float4*)(src + 4);
    }
    __syncthreads();
#pragma unroll
    for (int kk = 0; kk < 16; ++kk) {
      float a8[8], b8[8];
      *(float4*)&a8[0] = *(const float4*)&As[kk][ty * 4];
      *(float4*)&a8[4] = *(const float4*)&As[kk][64 + ty * 4];
      *(float4*)&b8[0] = *(const float4*)&Bs[kk][tx * 4];
      *(float4*)&b8[4] = *(const float4*)&Bs[kk][64 + tx * 4];
#pragma unroll
      for (int i = 0; i < 8; ++i)
#pragma unroll
        for (int jj = 0; jj < 8; ++jj) acc[i][jj] = fmaf(a8[i], b8[jj], acc[i][jj]);
    }
    __syncthreads();
  }
  if (CCOMP) {
#pragma unroll
    for (int hr = 0; hr < 2; ++hr) {
      int TI = 2 * ti + hr;
#pragma unroll
      for (int hc = 0; hc < 2; ++hc) {
        int TJ = 2 * tj + hc;
        if (TJ > TI) continue;
        float* C = Cb + ((size_t)TI * (TI + 1) / 2 + TJ) * 4096;
#pragma unroll
        for (int i = 0; i < 4; ++i) {
          if (ATOMIC) {
            float* pbase = &C[(ty * 4 + i) * 64 + tx * 4];
            atomicAdd(pbase + 0, alpha * acc[hr * 4 + i][hc * 4 + 0]);
            atomicAdd(pbase + 1, alpha * acc[hr * 4 + i][hc * 4 + 1]);
            atomicAdd(pbase + 2, alpha * acc[hr * 4 + i][hc * 4 + 2]);
            atomicAdd(pbase + 3, alpha * acc[hr * 4 + i][hc * 4 + 3]);
          } else {
            float4 c;
            c.x = alpha * acc[hr * 4 + i][hc * 4 + 0];
            c.y = alpha * acc[hr * 4 + i][hc * 4 + 1];
            c.z = alpha * acc[hr * 4 + i][hc * 4 + 2];
            c.w = alpha * acc[hr * 4 + i][hc * 4 + 3];
            *(float4*)&C[(ty * 4 + i) * 64 + tx * 4] = c;
          }
        }
      }
    }
  } else {
    float* C = Cb + (long long)blockIdx.z * cZ;
#pragma unroll
    for (int i = 0; i < 8; ++i) {
      int row = (i < 4) ? (m0 + ty * 4 + i) : (m0 + 64 + ty * 4 + i - 4);
      float* dst0 = &C[(size_t)row * ldc + n0 + tx * 4];
      float* dst1 = dst0 + 64;
      float4 c0, c1;
      c0.x = alpha * acc[i][0]; c0.y = alpha * acc[i][1];
      c0.z = alpha * acc[i][2]; c0.w = alpha * acc[i][3];
      c1.x = alpha * acc[i][4]; c1.y = alpha * acc[i][5];
      c1.z = alpha * acc[i][6]; c1.w = alpha * acc[i][7];
      if (ACCUM) {
        float4 o0 = *(float4*)dst0, o1 = *(float4*)dst1;
        c0.x += o0.x; c0.y += o0.y; c0.z += o0.z; c0.w += o0.w;
        c1.x += o1.x; c1.y += o1.y; c1.z += o1.z; c1.w += o1.w;
      }
      *(float4*)dst0 = c0;
      *(float4*)dst1 = c1;
    }
  }
}

// ---------------- zero strict upper + put Ginv blocks on diagonal ----------------
__global__ __launch_bounds__(256) void finish_W_prep(float* __restrict__ A,
                                                     const float* __restrict__ GinvAll) {
  size_t q = (size_t)blockIdx.x * 256 + threadIdx.x;
  int r = (int)(q >> 10), c4 = (int)(q & 1023) << 2;
  int rb = r >> 6, cb = c4 >> 6;
  if (cb == rb) {
    const float* g = GinvAll + (size_t)rb * 4096 + (size_t)(r & 63) * 64 + (c4 & 63);
    *(float4*)&A[q * 4] = *(const float4*)g;
  } else if (cb > rb) {
    *(float4*)&A[q * 4] = make_float4(0.f, 0.f, 0.f, 0.f);
  }
}

// ---------------- diag + final R ----------------
__global__ __launch_bounds__(256) void copy_diag(const float* __restrict__ Mc,
                                                 float* __restrict__ d) {
  int i = blockIdx.x * 256 + threadIdx.x;
  int tb = i >> 6;
  size_t q = (size_t)tb * (tb + 1) / 2 + tb;
  d[i] = Mc[q * 4096 + (size_t)(i & 63) * 65];
}

__global__ __launch_bounds__(256) void final_R(const float* __restrict__ Mc,
                                               const float* __restrict__ d,
                                               float* __restrict__ out) {
  size_t idx = (size_t)blockIdx.x * 256 + threadIdx.x;
  int r = (int)(idx >> 12), c = (int)(idx & 4095);
  int a = r > c ? r : c, b = r > c ? c : r;
  int ta = a >> 6, tb = b >> 6;
  size_t q = (size_t)ta * (ta + 1) / 2 + tb;
  float m = Mc[q * 4096 + (size_t)(a & 63) * 64 + (b & 63)];
  out[idx] = d[r] + d[c] - 2.0f * m;
}

// ---------------- launch ----------------
extern "C" void kernel_launch(void* const* d_in, const int* in_sizes, int n_in,
                              void* d_out, int out_size, void* d_ws, size_t ws_size,
                              hipStream_t stream) {
  const int* eidx = (const int*)d_in[1];
  const float* ef = (const float*)d_in[2];
  const float* sW1 = (const float*)d_in[4],  *sb1 = (const float*)d_in[5];
  const float* sW2 = (const float*)d_in[6],  *sb2 = (const float*)d_in[7];
  const float* sW3 = (const float*)d_in[8],  *sb3 = (const float*)d_in[9];
  const float* pW1 = (const float*)d_in[10], *pb1 = (const float*)d_in[11];
  const float* pW2 = (const float*)d_in[12], *pb2 = (const float*)d_in[13];
  const float* pW3 = (const float*)d_in[14], *pb3 = (const float*)d_in[15];

  float* dout = (float*)d_out;
  float* dA = dout;                       // A/G/W scribble space = R region
  float* outS = dout + (size_t)NN * NN;   // shared (131072)
  float* outP = outS + NEDGE;             // species (131072)

  float* ws = (float*)d_ws;
  float* Mc = ws;                         // 2080 * 4096 floats
  float* U = ws + 8519680ull;             // union region (4,194,304 floats)
  float* cond = U;                        // live: mlp -> scatter
  float* Ginv = U;                        // live: chol -> finish_W_prep
  float* Tbuf = U;                        // live: doubling
  float* diagb = U;                       // live: copy_diag -> final_R

  mlp_kernel<<<NEDGE / 256, 256, 0, stream>>>(ef, sW1, sb1, sW2, sb2, sW3, sb3,
                                              pW1, pb1, pW2, pb2, pW3, pb3,
                                              outS, outP, cond);
  zero_ws<<<2080, 256, 0, stream>>>(Mc);  // Mc = 0 for atomic wtw
  init_A<<<(NN * NN / 4) / 256, 256, 0, stream>>>(dA);
  scatter_kernel<<<NEDGE / 256, 256, 0, stream>>>(eidx, cond, dA);

  // ---- panel-256 blocked Cholesky: 3 dispatches per panel ----
  for (int p = 0; p < 16; ++p) {
    potrf_diag256<<<1, 512, 0, stream>>>(dA, Ginv, p);
    int rem = NN - (p + 1) * 256;
    if (rem > 0) {
      trsm_panel256<<<rem / 64, 256, 0, stream>>>(dA, Ginv, p);
      int nt = rem / 128;
      float* Lp = dA + (size_t)((p + 1) * 256) * LDA + (size_t)p * 256;
      float* trail = dA + (size_t)((p + 1) * 256) * (LDA + 1);
      gemm128<false, true, true, true, false, false, false, false>
          <<<dim3(nt * (nt + 1) / 2, 1, 1), 256, 0, stream>>>(
              Lp, 0, LDA, Lp, 0, LDA, trail, 0, LDA, 256, -1.0f);
    }
  }

  finish_W_prep<<<(NN * NN / 4) / 256, 256, 0, stream>>>(dA, Ginv);

  // W = G^{-1} by recursive doubling: W21 = -W22 * (L21 * W11)
  for (int S = 64; S <= 2048; S *= 2) {
    int np = NN / (2 * S);
    long long pz = (long long)2 * S * (LDA + 1);
    if (S == 64) {
      gemm64<false, false, false, false, false, false>
          <<<dim3(1, 1, np), 256, 0, stream>>>(
              dA + (size_t)S * LDA, pz, LDA, dA, pz, LDA,
              Tbuf, (long long)S * S, S, S, 1.0f);
      gemm64<false, false, false, false, false, false>
          <<<dim3(1, 1, np), 256, 0, stream>>>(
              dA + (size_t)S * (LDA + 1), pz, LDA, Tbuf, (long long)S * S, S,
              dA + (size_t)S * LDA, pz, LDA, S, -1.0f);
    } else {
      gemm128<false, false, false, false, false, false, false, false>
          <<<dim3(S / 128, S / 128, np), 256, 0, stream>>>(
              dA + (size_t)S * LDA, pz, LDA, dA, pz, LDA,
              Tbuf, (long long)S * S, S, S, 1.0f);
      gemm128<false, false, false, false, false, false, false, false>
          <<<dim3(S / 128, S / 128, np), 256, 0, stream>>>(
              dA + (size_t)S * (LDA + 1), pz, LDA, Tbuf, (long long)S * S, S,
              dA + (size_t)S * LDA, pz, LDA, S, -1.0f);
    }
  }

  // Ainv = W^T W into compact lower 64-tiles, split-K=2, atomic accumulate
  gemm128<true, false, false, true, true, true, true, true>
      <<<dim3(528, 1, 2), 256, 0, stream>>>(dA, 0, LDA, dA, 0, LDA, Mc, 0, 64,
                                            NN, 1.0f);

  copy_diag<<<NN / 256, 256, 0, stream>>>(Mc, diagb);
  final_R<<<(NN * NN) / 256, 256, 0, stream>>>(Mc, diagb, dout);
}